// Round 4
// baseline (1080.380 us; speedup 1.0000x reference)
//
#include <hip/hip_runtime.h>
#include <hip/hip_bf16.h>
#include <stdint.h>

typedef __attribute__((ext_vector_type(8))) short s8v;   // 8 bf16 = K32 MFMA A/B frag
typedef __attribute__((ext_vector_type(4))) short s4v;   // 4 bf16 = K16 MFMA A/B frag
typedef __attribute__((ext_vector_type(4))) float f4v;   // MFMA C/D frag

#define NE   128
#define NT   2048
#define DIN  128
#define DH   512
#define DOUT 128

#define MFMA32(a,b,c) __builtin_amdgcn_mfma_f32_16x16x32_bf16(a,b,c,0,0,0)
// gfx90a-era builtin, valid on gfx950 (v_mfma_f32_16x16x16_bf16, A/B = short4).
// NOTE: do NOT guard with __has_builtin — it returns false in the HOST pass.
#define MFMA16(a,b,c) __builtin_amdgcn_mfma_f32_16x16x16bf16_1k(a,b,c,0,0,0)

// async global->LDS, 16B per lane; LDS dest must be wave-uniform base + lane*16
#define GLOAD16(g,l) __builtin_amdgcn_global_load_lds( \
    (const __attribute__((address_space(1))) void*)(g), \
    (__attribute__((address_space(3))) void*)(l), 16, 0, 0)

// counted vmcnt wait (T4)
#define WAIT_VM(N) asm volatile("s_waitcnt vmcnt(" #N ")" ::: "memory")
// raw barrier (no implicit vmcnt(0) drain, unlike __syncthreads)
#define BAR() do { asm volatile("" ::: "memory"); \
                   __builtin_amdgcn_s_barrier();  \
                   asm volatile("" ::: "memory"); } while (0)

__device__ __forceinline__ __hip_bfloat162 pk2(float a, float b) {
  float2 t; t.x = a; t.y = b;
  return __float22bfloat162_rn(t);
}

__device__ __forceinline__ s8v pack8(float4 a, float4 b) {
  union { s8v v; __hip_bfloat162 h[4]; } u;
  u.h[0] = pk2(a.x, a.y); u.h[1] = pk2(a.z, a.w);
  u.h[2] = pk2(b.x, b.y); u.h[3] = pk2(b.z, b.w);
  return u.v;
}

// gelu(x) = x * sigmoid(x*(1.5957691 + 0.07135481*x^2))  (tanh-form rewritten)
__device__ __forceinline__ float gelu_f(float x) {
  float x2 = x * x;
  float p  = __builtin_fmaf(x2, 0.07135481f, 1.5957691f);
  float e  = __expf(-x * p);
  return x * __builtin_amdgcn_rcpf(1.0f + e);
}

// ---------------- merged prep kernel ----------------
// Grid = NE*4 (W1 path) + NE*32 (W2 path). Merging lets the two independent
// transforms overlap instead of serializing on the stream.
//
// W1 path: block=(e,ks) reads rows d in [32ks,32ks+32) CONTIGUOUSLY (8 lanes x
// 64B = 512B/row segments), transposes through LDS in 4 h-chunks of 128.
// W1F layout: [e][ht 0..31][ks 0..3][lane 0..63][8 bf16]; frag value j =
// W1[e][d = ks*32 + (lane>>4)*8 + j][h = ht*16 + (lane&15)]
//
// W2 path: unchanged logic (reads already contiguous).
// W2F layout: [e][ht 0..31][ot 0..7][lane 0..63][4 bf16]; frag value j =
// W2[e][h = ht*16 + (lane>>4)*4 + j][o = ot*16 + (lane&15)]
#define W1_BLOCKS (NE * 4)
__global__ __launch_bounds__(256) void pack_weights(
    const float* __restrict__ W1, const float* __restrict__ W2,
    ushort* __restrict__ W1F, ushort* __restrict__ W2F) {
  __shared__ __align__(16) float T[32 * 132];   // 16.9 KB, shared by both paths
  const int tid = threadIdx.x;

  if ((int)blockIdx.x < W1_BLOCKS) {
    const int e = blockIdx.x >> 2, ks = blockIdx.x & 3;
    const float* We = W1 + (size_t)e * (DIN * DH) + (size_t)(ks * 32) * DH;
    const int r = tid >> 3, c0 = (tid & 7) * 16;   // load map: contiguous 64B/thread
    const int lane = tid & 63, wid = tid >> 6;
    const int q = lane >> 4, l16 = lane & 15;
    for (int hc = 0; hc < 4; ++hc) {
      if (hc) __syncthreads();                    // T reuse: reads done before rewrite
      const float* src = We + (size_t)r * DH + hc * 128 + c0;
      float4 v0 = *(const float4*)(src + 0);
      float4 v1 = *(const float4*)(src + 4);
      float4 v2 = *(const float4*)(src + 8);
      float4 v3 = *(const float4*)(src + 12);
      float* t = &T[r * 132 + c0];
      *(float4*)(t + 0) = v0; *(float4*)(t + 4)  = v1;
      *(float4*)(t + 8) = v2; *(float4*)(t + 12) = v3;
      __syncthreads();
#pragma unroll
      for (int i = 0; i < 2; ++i) {
        const int htl = wid + 4 * i;              // 0..7
        const int ht  = hc * 8 + htl;
        float g[8];
#pragma unroll
        for (int j = 0; j < 8; ++j) g[j] = T[(8 * q + j) * 132 + 16 * htl + l16];
        float4 a; a.x = g[0]; a.y = g[1]; a.z = g[2]; a.w = g[3];
        float4 b; b.x = g[4]; b.y = g[5]; b.z = g[6]; b.w = g[7];
        *(s8v*)(W1F + ((((size_t)e * 32 + ht) * 4) + ks) * 512 + lane * 8) = pack8(a, b);
      }
    }
  } else {
    const int bb = (int)blockIdx.x - W1_BLOCKS;
    const int e = bb >> 5, ht = bb & 31;
    float (*T2)[132] = (float (*)[132])T;
    const int h = tid >> 4, c16 = tid & 15;
    const float* src = W2 + (size_t)e * (DH * DOUT) + (size_t)(ht * 16 + h) * DOUT + c16 * 8;
    float4 v0 = *(const float4*)src;
    float4 v1 = *(const float4*)(src + 4);
    float* trow = &T2[h][c16 * 8];
    *(float4*)(trow + 0) = v0; *(float4*)(trow + 4) = v1;
    __syncthreads();
    const int lane = tid & 63;
    const int q = lane >> 4, l16 = lane & 15;
#pragma unroll
    for (int i = 0; i < 2; ++i) {
      int ot = (tid >> 6) + i * 4;
      float g0 = T2[4 * q + 0][ot * 16 + l16];
      float g1 = T2[4 * q + 1][ot * 16 + l16];
      float g2 = T2[4 * q + 2][ot * 16 + l16];
      float g3 = T2[4 * q + 3][ot * 16 + l16];
      union { s4v v; __hip_bfloat162 h2[2]; } u;
      u.h2[0] = pk2(g0, g1); u.h2[1] = pk2(g2, g3);
      *(s4v*)(W2F + (((size_t)e * 32 + ht) * 8 + ot) * 256 + lane * 4) = u.v;
    }
  }
}

// ---------------- fused main kernel ----------------
// Block = 128 tokens of one expert, 4 waves; wave w owns m-range [32w, 32w+32).
// X frags live in VGPRs for the whole block. Stage1 (K=32): Ht = W1 . X^T ->
// D regs ARE the K16 A-frag after gelu+pack. Stage2 (K=16): out += gelu(H).W2.
// Pipeline: 2 LDS buffers (32 KB total -> 5 blocks/CU, the occupancy lever:
// measured 27% occ / 28% MfmaUtil at 3 blocks was latency-bound), depth-1
// prefetch, counted vmcnt(4) + raw barriers (no vmcnt(0) drain in-loop).
// Weights are L2-resident (XCD swizzle) so depth-1 covers their latency.
__global__ __launch_bounds__(256, 5) void moe_fused(
    const float* __restrict__ X, const ushort* __restrict__ W1F,
    const ushort* __restrict__ W2F, float* __restrict__ Out) {
  __shared__ __align__(16) ushort W1s[2][4096];  // chunk: 2 htiles x 4 ks x 512
  __shared__ __align__(16) ushort W2s[2][4096];  // chunk: 2 htiles x 8 ot x 256

  const int tid  = threadIdx.x;
  const int lane = tid & 63;
  const int wid  = tid >> 6;
  const int q    = lane >> 4;
  const int l16  = lane & 15;

  // XCD swizzle: grid 2048 = 8 XCDs x 256 blocks (round-robin assumption).
  // XCD x gets work ids [x*256, x*256+256) = experts [x*16, x*16+16), all tiles.
  const int bid  = blockIdx.x;
  const int wk   = ((bid & 7) << 8) | (bid >> 3);
  const int e    = wk >> 4;
  const int tile = wk & 15;

  const float* Xe  = X + ((size_t)e * NT + (size_t)tile * 128) * DIN;
  const ushort* W1e = W1F + (size_t)e * 65536;
  const ushort* W2e = W2F + (size_t)e * 65536;
  float* Oe = Out + ((size_t)e * NT + (size_t)tile * 128) * DOUT;

  // ---- load this wave's X fragments into registers (once) ----
  s8v xf[2][4];
#pragma unroll
  for (int mt = 0; mt < 2; ++mt) {
#pragma unroll
    for (int ks = 0; ks < 4; ++ks) {
      const float* p = Xe + (size_t)(wid * 32 + mt * 16 + l16) * DIN + ks * 32 + q * 8;
      float4 v0 = *(const float4*)p;
      float4 v1 = *(const float4*)(p + 4);
      xf[mt][ks] = pack8(v0, v1);
    }
  }

  const f4v zero4 = {0.0f, 0.0f, 0.0f, 0.0f};
  f4v oacc[2][8];
#pragma unroll
  for (int mt = 0; mt < 2; ++mt)
#pragma unroll
    for (int ot = 0; ot < 8; ++ot) oacc[mt][ot] = zero4;

  // issue 4 global_load_lds per thread for one chunk (2x W1 + 2x W2)
  auto stage = [&](int chunk, int b) {
    const ushort* g1 = W1e + chunk * 4096;
    const ushort* g2 = W2e + chunk * 4096;
#pragma unroll
    for (int i = 0; i < 2; ++i) {
      int u = i * 256 + tid;
      GLOAD16(g1 + u * 8, &W1s[b][u * 8]);
      GLOAD16(g2 + u * 8, &W2s[b][u * 8]);
    }
  };

  // keep the xf float4 loads ordered before the staged GLOADs so the vmcnt
  // bookkeeping in the loop counts only weight loads
  asm volatile("" ::: "memory");

  // ---- prologue: chunk 0 into buf 0 (4 loads/thread in flight) ----
  stage(0, 0);

  for (int c = 0; c < 16; ++c) {
    const int buf = c & 1;
    if (c < 15) stage(c + 1, buf ^ 1);   // depth-1 prefetch into other buffer
    // wait for chunk c's 4 loads; chunk c+1 stays in flight across the barrier
    if (c < 15) { WAIT_VM(4); } else { WAIT_VM(0); }
    BAR();   // everyone waited -> all waves' chunk-c LDS writes are visible

#pragma unroll
    for (int hl = 0; hl < 2; ++hl) {
      // stage 1: K=32 over d, one 16-h tile
      f4v hacc[2]; hacc[0] = zero4; hacc[1] = zero4;
      s8v af[4];
#pragma unroll
      for (int ks = 0; ks < 4; ++ks)
        af[ks] = *(const s8v*)&W1s[buf][(hl * 4 + ks) * 512 + lane * 8];
      __builtin_amdgcn_s_setprio(1);
#pragma unroll
      for (int ks = 0; ks < 4; ++ks) {
        hacc[0] = MFMA32(af[ks], xf[0][ks], hacc[0]);
        hacc[1] = MFMA32(af[ks], xf[1][ks], hacc[1]);
      }
      __builtin_amdgcn_s_setprio(0);
      // gelu + pack: D regs (m=l16, h=4q+r) == K16 A-frag (row=l16, k=4q+j)
      s4v a2[2];
#pragma unroll
      for (int mt = 0; mt < 2; ++mt) {
        union { s4v v; __hip_bfloat162 h2[2]; } u;
        u.h2[0] = pk2(gelu_f(hacc[mt][0]), gelu_f(hacc[mt][1]));
        u.h2[1] = pk2(gelu_f(hacc[mt][2]), gelu_f(hacc[mt][3]));
        a2[mt] = u.v;
      }
      // stage 2: K=16, 8 o-tiles
      s4v bfr[8];
#pragma unroll
      for (int ot = 0; ot < 8; ++ot)
        bfr[ot] = *(const s4v*)&W2s[buf][(hl * 8 + ot) * 256 + lane * 4];
      __builtin_amdgcn_s_setprio(1);
#pragma unroll
      for (int ot = 0; ot < 8; ++ot) {
        oacc[0][ot] = MFMA16(a2[0], bfr[ot], oacc[0][ot]);
        oacc[1][ot] = MFMA16(a2[1], bfr[ot], oacc[1][ot]);
      }
      __builtin_amdgcn_s_setprio(0);
    }

    BAR();   // all waves done reading buf before it is restaged next iter
  }

  // ---- epilogue: D layout col=o=l16, row m = 4q + r ----
#pragma unroll
  for (int mt = 0; mt < 2; ++mt) {
    const int mb = wid * 32 + mt * 16 + 4 * q;
#pragma unroll
    for (int ot = 0; ot < 8; ++ot) {
      float* p = Oe + (size_t)mb * DOUT + ot * 16 + l16;
      p[0 * DOUT] = oacc[mt][ot][0];
      p[1 * DOUT] = oacc[mt][ot][1];
      p[2 * DOUT] = oacc[mt][ot][2];
      p[3 * DOUT] = oacc[mt][ot][3];
    }
  }
}

extern "C" void kernel_launch(void* const* d_in, const int* in_sizes, int n_in,
                              void* d_out, int out_size, void* d_ws, size_t ws_size,
                              hipStream_t stream) {
  const float* X  = (const float*)d_in[0];
  const float* W1 = (const float*)d_in[1];
  const float* W2 = (const float*)d_in[2];
  float* Out = (float*)d_out;

  ushort* W1F = (ushort*)d_ws;                             // 128 KB/expert = 16.8 MB
  ushort* W2F = (ushort*)d_ws + (size_t)NE * 65536;        // 128 KB/expert = 16.8 MB

  pack_weights<<<NE * 4 + NE * 32, 256, 0, stream>>>(W1, W2, W1F, W2F);
  moe_fused<<<NE * (NT / 128), 256, 0, stream>>>(X, W1F, W2F, Out);
}

// Round 6
// 340.409 us; speedup vs baseline: 3.1738x; 3.1738x over previous
//
#include <hip/hip_runtime.h>
#include <hip/hip_bf16.h>
#include <stdint.h>

typedef __attribute__((ext_vector_type(8))) short s8v;   // 8 bf16 = K32 MFMA A/B frag
typedef __attribute__((ext_vector_type(4))) short s4v;   // 4 bf16 = K16 MFMA A/B frag
typedef __attribute__((ext_vector_type(4))) float f4v;   // MFMA C/D frag

#define NE   128
#define NT   2048
#define DIN  128
#define DH   512
#define DOUT 128

#define MFMA32(a,b,c) __builtin_amdgcn_mfma_f32_16x16x32_bf16(a,b,c,0,0,0)
// gfx90a-era builtin, valid on gfx950 (v_mfma_f32_16x16x16_bf16, A/B = short4).
// NOTE: do NOT guard with __has_builtin — it returns false in the HOST pass.
#define MFMA16(a,b,c) __builtin_amdgcn_mfma_f32_16x16x16bf16_1k(a,b,c,0,0,0)

// async global->LDS, 16B per lane; LDS dest must be wave-uniform base + lane*16
#define GLOAD16(g,l) __builtin_amdgcn_global_load_lds( \
    (const __attribute__((address_space(1))) void*)(g), \
    (__attribute__((address_space(3))) void*)(l), 16, 0, 0)

// counted vmcnt wait (T4)
#define WAIT_VM(N) asm volatile("s_waitcnt vmcnt(" #N ")" ::: "memory")
// raw barrier (no implicit vmcnt(0) drain, unlike __syncthreads)
#define BAR() do { asm volatile("" ::: "memory"); \
                   __builtin_amdgcn_s_barrier();  \
                   asm volatile("" ::: "memory"); } while (0)

__device__ __forceinline__ __hip_bfloat162 pk2(float a, float b) {
  float2 t; t.x = a; t.y = b;
  return __float22bfloat162_rn(t);
}

__device__ __forceinline__ s8v pack8(float4 a, float4 b) {
  union { s8v v; __hip_bfloat162 h[4]; } u;
  u.h[0] = pk2(a.x, a.y); u.h[1] = pk2(a.z, a.w);
  u.h[2] = pk2(b.x, b.y); u.h[3] = pk2(b.z, b.w);
  return u.v;
}

// gelu(x) = x * sigmoid(x*(1.5957691 + 0.07135481*x^2))  (tanh-form rewritten)
__device__ __forceinline__ float gelu_f(float x) {
  float x2 = x * x;
  float p  = __builtin_fmaf(x2, 0.07135481f, 1.5957691f);
  float e  = __expf(-x * p);
  return x * __builtin_amdgcn_rcpf(1.0f + e);
}

// ---------------- merged prep kernel ----------------
// Grid = NE*4 (W1 path) + NE*32 (W2 path). Merging lets the two independent
// transforms overlap instead of serializing on the stream.
//
// W1 path: block=(e,ks) reads rows d in [32ks,32ks+32) CONTIGUOUSLY (8 lanes x
// 64B = 512B/row segments), transposes through LDS in 4 h-chunks of 128.
// W1F layout: [e][ht 0..31][ks 0..3][lane 0..63][8 bf16]; frag value j =
// W1[e][d = ks*32 + (lane>>4)*8 + j][h = ht*16 + (lane&15)]
//
// W2 path: reads already contiguous.
// W2F layout: [e][ht 0..31][ot 0..7][lane 0..63][4 bf16]; frag value j =
// W2[e][h = ht*16 + (lane>>4)*4 + j][o = ot*16 + (lane&15)]
#define W1_BLOCKS (NE * 4)
__global__ __launch_bounds__(256) void pack_weights(
    const float* __restrict__ W1, const float* __restrict__ W2,
    ushort* __restrict__ W1F, ushort* __restrict__ W2F) {
  __shared__ __align__(16) float T[32 * 132];   // 16.9 KB, shared by both paths
  const int tid = threadIdx.x;

  if ((int)blockIdx.x < W1_BLOCKS) {
    const int e = blockIdx.x >> 2, ks = blockIdx.x & 3;
    const float* We = W1 + (size_t)e * (DIN * DH) + (size_t)(ks * 32) * DH;
    const int r = tid >> 3, c0 = (tid & 7) * 16;   // load map: contiguous 64B/thread
    const int lane = tid & 63, wid = tid >> 6;
    const int q = lane >> 4, l16 = lane & 15;
    for (int hc = 0; hc < 4; ++hc) {
      if (hc) __syncthreads();                    // T reuse: reads done before rewrite
      const float* src = We + (size_t)r * DH + hc * 128 + c0;
      float4 v0 = *(const float4*)(src + 0);
      float4 v1 = *(const float4*)(src + 4);
      float4 v2 = *(const float4*)(src + 8);
      float4 v3 = *(const float4*)(src + 12);
      float* t = &T[r * 132 + c0];
      *(float4*)(t + 0) = v0; *(float4*)(t + 4)  = v1;
      *(float4*)(t + 8) = v2; *(float4*)(t + 12) = v3;
      __syncthreads();
#pragma unroll
      for (int i = 0; i < 2; ++i) {
        const int htl = wid + 4 * i;              // 0..7
        const int ht  = hc * 8 + htl;
        float g[8];
#pragma unroll
        for (int j = 0; j < 8; ++j) g[j] = T[(8 * q + j) * 132 + 16 * htl + l16];
        float4 a; a.x = g[0]; a.y = g[1]; a.z = g[2]; a.w = g[3];
        float4 b; b.x = g[4]; b.y = g[5]; b.z = g[6]; b.w = g[7];
        *(s8v*)(W1F + ((((size_t)e * 32 + ht) * 4) + ks) * 512 + lane * 8) = pack8(a, b);
      }
    }
  } else {
    const int bb = (int)blockIdx.x - W1_BLOCKS;
    const int e = bb >> 5, ht = bb & 31;
    float (*T2)[132] = (float (*)[132])T;
    const int h = tid >> 4, c16 = tid & 15;
    const float* src = W2 + (size_t)e * (DH * DOUT) + (size_t)(ht * 16 + h) * DOUT + c16 * 8;
    float4 v0 = *(const float4*)src;
    float4 v1 = *(const float4*)(src + 4);
    float* trow = &T2[h][c16 * 8];
    *(float4*)(trow + 0) = v0; *(float4*)(trow + 4) = v1;
    __syncthreads();
    const int lane = tid & 63;
    const int q = lane >> 4, l16 = lane & 15;
#pragma unroll
    for (int i = 0; i < 2; ++i) {
      int ot = (tid >> 6) + i * 4;
      float g0 = T2[4 * q + 0][ot * 16 + l16];
      float g1 = T2[4 * q + 1][ot * 16 + l16];
      float g2 = T2[4 * q + 2][ot * 16 + l16];
      float g3 = T2[4 * q + 3][ot * 16 + l16];
      union { s4v v; __hip_bfloat162 h2[2]; } u;
      u.h2[0] = pk2(g0, g1); u.h2[1] = pk2(g2, g3);
      *(s4v*)(W2F + (((size_t)e * 32 + ht) * 8 + ot) * 256 + lane * 4) = u.v;
    }
  }
}

// ---------------- fused main kernel ----------------
// Block = 128 tokens of one expert, 4 waves; wave w owns m-range [32w, 32w+32).
// X frags live in VGPRs for the whole block. Stage1 (K=32): Ht = W1 . X^T ->
// D regs ARE the K16 A-frag after gelu+pack. Stage2 (K=16): out += gelu(H).W2.
//
// Registers: ~68 arch VGPR + 64 AGPR (oacc) = ~132 unified -> fits the
// 3-waves/SIMD budget (170) but NOT 4 (128) or 5 (102). Round 4 proved
// (256,5) spills oacc to scratch: 4.2 GB HBM traffic, 6x regression.
// Occupancy is register-capped at 3 blocks/CU, so instead of raising it we
// halve the sync count: ONE barrier per chunk. Phase c:
//   WAIT_VM(4)  -- my chunk-c loads done (c+1, c+2 stay in flight)
//   BAR         -- all waves waited => all chunk-c LDS writes visible;
//                  also: all waves finished phase c-1 reads => the buffer
//                  (c+2)%3 == (c-1)%3 is free for restage (WAR safe)
//   stage(c+2)  -- depth-2 prefetch, issued after af-reads of hl=0
//   compute chunk c
__global__ __launch_bounds__(256, 3) void moe_fused(
    const float* __restrict__ X, const ushort* __restrict__ W1F,
    const ushort* __restrict__ W2F, float* __restrict__ Out) {
  __shared__ __align__(16) ushort W1s[3][4096];  // chunk: 2 htiles x 4 ks x 512
  __shared__ __align__(16) ushort W2s[3][4096];  // chunk: 2 htiles x 8 ot x 256

  const int tid  = threadIdx.x;
  const int lane = tid & 63;
  const int wid  = tid >> 6;
  const int q    = lane >> 4;
  const int l16  = lane & 15;

  // XCD swizzle: grid 2048 = 8 XCDs x 256 blocks (round-robin assumption).
  // XCD x gets work ids [x*256, x*256+256) = experts [x*16, x*16+16), all tiles.
  const int bid  = blockIdx.x;
  const int wk   = ((bid & 7) << 8) | (bid >> 3);
  const int e    = wk >> 4;
  const int tile = wk & 15;

  const float* Xe  = X + ((size_t)e * NT + (size_t)tile * 128) * DIN;
  const ushort* W1e = W1F + (size_t)e * 65536;
  const ushort* W2e = W2F + (size_t)e * 65536;
  float* Oe = Out + ((size_t)e * NT + (size_t)tile * 128) * DOUT;

  // ---- load this wave's X fragments into registers (once) ----
  s8v xf[2][4];
#pragma unroll
  for (int mt = 0; mt < 2; ++mt) {
#pragma unroll
    for (int ks = 0; ks < 4; ++ks) {
      const float* p = Xe + (size_t)(wid * 32 + mt * 16 + l16) * DIN + ks * 32 + q * 8;
      float4 v0 = *(const float4*)p;
      float4 v1 = *(const float4*)(p + 4);
      xf[mt][ks] = pack8(v0, v1);
    }
  }

  const f4v zero4 = {0.0f, 0.0f, 0.0f, 0.0f};
  f4v oacc[2][8];
#pragma unroll
  for (int mt = 0; mt < 2; ++mt)
#pragma unroll
    for (int ot = 0; ot < 8; ++ot) oacc[mt][ot] = zero4;

  // issue 4 global_load_lds per thread for one chunk (2x W1 + 2x W2)
  auto stage = [&](int chunk, int b) {
    const ushort* g1 = W1e + chunk * 4096;
    const ushort* g2 = W2e + chunk * 4096;
#pragma unroll
    for (int i = 0; i < 2; ++i) {
      int u = i * 256 + tid;
      GLOAD16(g1 + u * 8, &W1s[b][u * 8]);
      GLOAD16(g2 + u * 8, &W2s[b][u * 8]);
    }
  };

  // keep the xf float4 loads ordered before the staged GLOADs so the vmcnt
  // bookkeeping in the loop counts only weight loads
  asm volatile("" ::: "memory");

  // ---- prologue: chunks 0,1 into bufs 0,1 (8 loads/thread in flight) ----
  stage(0, 0);
  stage(1, 1);

  int buf = 0;                       // buf == c % 3
  for (int c = 0; c < 16; ++c) {
    // wait for chunk c's 4 loads; chunks c+1 (and c+2 after stage) in flight
    if (c < 14)       { WAIT_VM(4); }
    else if (c == 14) { WAIT_VM(4); }
    else              { WAIT_VM(0); }
    BAR();   // single barrier per chunk (see header comment for WAR proof)

    // hl = 0: issue af reads first so ds_read latency overlaps the stage issue
    f4v hacc[2]; hacc[0] = zero4; hacc[1] = zero4;
    s8v af[4];
#pragma unroll
    for (int ks = 0; ks < 4; ++ks)
      af[ks] = *(const s8v*)&W1s[buf][ks * 512 + lane * 8];

    if (c < 14) {                    // depth-2 prefetch into the freed buffer
      int nb = buf + 2; if (nb >= 3) nb -= 3;
      stage(c + 2, nb);
    }

#pragma unroll
    for (int hl = 0; hl < 2; ++hl) {
      if (hl) {                      // af reads for hl=1 (hl=0 done above)
#pragma unroll
        for (int ks = 0; ks < 4; ++ks)
          af[ks] = *(const s8v*)&W1s[buf][(4 + ks) * 512 + lane * 8];
        hacc[0] = zero4; hacc[1] = zero4;
      }
      __builtin_amdgcn_s_setprio(1);
#pragma unroll
      for (int ks = 0; ks < 4; ++ks) {
        hacc[0] = MFMA32(af[ks], xf[0][ks], hacc[0]);
        hacc[1] = MFMA32(af[ks], xf[1][ks], hacc[1]);
      }
      __builtin_amdgcn_s_setprio(0);
      // gelu + pack: D regs (m=l16, h=4q+r) == K16 A-frag (row=l16, k=4q+j)
      s4v a2[2];
#pragma unroll
      for (int mt = 0; mt < 2; ++mt) {
        union { s4v v; __hip_bfloat162 h2[2]; } u;
        u.h2[0] = pk2(gelu_f(hacc[mt][0]), gelu_f(hacc[mt][1]));
        u.h2[1] = pk2(gelu_f(hacc[mt][2]), gelu_f(hacc[mt][3]));
        a2[mt] = u.v;
      }
      // stage 2: K=16, 8 o-tiles
      s4v bfr[8];
#pragma unroll
      for (int ot = 0; ot < 8; ++ot)
        bfr[ot] = *(const s4v*)&W2s[buf][(hl * 8 + ot) * 256 + lane * 4];
      __builtin_amdgcn_s_setprio(1);
#pragma unroll
      for (int ot = 0; ot < 8; ++ot) {
        oacc[0][ot] = MFMA16(a2[0], bfr[ot], oacc[0][ot]);
        oacc[1][ot] = MFMA16(a2[1], bfr[ot], oacc[1][ot]);
      }
      __builtin_amdgcn_s_setprio(0);
    }

    ++buf; if (buf == 3) buf = 0;
  }

  // ---- epilogue: D layout col=o=l16, row m = 4q + r ----
#pragma unroll
  for (int mt = 0; mt < 2; ++mt) {
    const int mb = wid * 32 + mt * 16 + 4 * q;
#pragma unroll
    for (int ot = 0; ot < 8; ++ot) {
      float* p = Oe + (size_t)mb * DOUT + ot * 16 + l16;
      p[0 * DOUT] = oacc[mt][ot][0];
      p[1 * DOUT] = oacc[mt][ot][1];
      p[2 * DOUT] = oacc[mt][ot][2];
      p[3 * DOUT] = oacc[mt][ot][3];
    }
  }
}

extern "C" void kernel_launch(void* const* d_in, const int* in_sizes, int n_in,
                              void* d_out, int out_size, void* d_ws, size_t ws_size,
                              hipStream_t stream) {
  const float* X  = (const float*)d_in[0];
  const float* W1 = (const float*)d_in[1];
  const float* W2 = (const float*)d_in[2];
  float* Out = (float*)d_out;

  ushort* W1F = (ushort*)d_ws;                             // 128 KB/expert = 16.8 MB
  ushort* W2F = (ushort*)d_ws + (size_t)NE * 65536;        // 128 KB/expert = 16.8 MB

  pack_weights<<<NE * 4 + NE * 32, 256, 0, stream>>>(W1, W2, W1F, W2F);
  moe_fused<<<NE * (NT / 128), 256, 0, stream>>>(X, W1F, W2F, Out);
}

// Round 7
// 336.731 us; speedup vs baseline: 3.2084x; 1.0109x over previous
//
#include <hip/hip_runtime.h>
#include <hip/hip_bf16.h>
#include <stdint.h>

typedef __attribute__((ext_vector_type(8))) short s8v;   // 8 bf16 = K32 MFMA A/B frag
typedef __attribute__((ext_vector_type(4))) short s4v;   // 4 bf16 = K16 MFMA A/B frag
typedef __attribute__((ext_vector_type(4))) float f4v;   // MFMA C/D frag

#define NE   128
#define NT   2048
#define DIN  128
#define DH   512
#define DOUT 128

#define MFMA32(a,b,c) __builtin_amdgcn_mfma_f32_16x16x32_bf16(a,b,c,0,0,0)
// gfx90a-era builtin, valid on gfx950 (v_mfma_f32_16x16x16_bf16, A/B = short4).
// NOTE: do NOT guard with __has_builtin — it returns false in the HOST pass.
#define MFMA16(a,b,c) __builtin_amdgcn_mfma_f32_16x16x16bf16_1k(a,b,c,0,0,0)

// async global->LDS, 16B per lane; LDS dest must be wave-uniform base + lane*16
#define GLOAD16(g,l) __builtin_amdgcn_global_load_lds( \
    (const __attribute__((address_space(1))) void*)(g), \
    (__attribute__((address_space(3))) void*)(l), 16, 0, 0)

// counted vmcnt wait (T4)
#define WAIT_VM(N) asm volatile("s_waitcnt vmcnt(" #N ")" ::: "memory")
// raw barrier (no implicit vmcnt(0) drain, unlike __syncthreads)
#define BAR() do { asm volatile("" ::: "memory"); \
                   __builtin_amdgcn_s_barrier();  \
                   asm volatile("" ::: "memory"); } while (0)

__device__ __forceinline__ __hip_bfloat162 pk2(float a, float b) {
  float2 t; t.x = a; t.y = b;
  return __float22bfloat162_rn(t);
}

__device__ __forceinline__ s8v pack8(float4 a, float4 b) {
  union { s8v v; __hip_bfloat162 h[4]; } u;
  u.h[0] = pk2(a.x, a.y); u.h[1] = pk2(a.z, a.w);
  u.h[2] = pk2(b.x, b.y); u.h[3] = pk2(b.z, b.w);
  return u.v;
}

// gelu(x) = x * sigmoid(x*(1.5957691 + 0.07135481*x^2))  (tanh-form rewritten)
__device__ __forceinline__ float gelu_f(float x) {
  float x2 = x * x;
  float p  = __builtin_fmaf(x2, 0.07135481f, 1.5957691f);
  float e  = __expf(-x * p);
  return x * __builtin_amdgcn_rcpf(1.0f + e);
}

// ---------------- merged prep kernel ----------------
// Grid = NE*4 (W1 path) + NE*32 (W2 path). Merging lets the two independent
// transforms overlap instead of serializing on the stream.
//
// W1 path: block=(e,ks) reads rows d in [32ks,32ks+32) CONTIGUOUSLY (8 lanes x
// 64B = 512B/row segments), transposes through LDS in 4 h-chunks of 128.
// W1F layout: [e][ht 0..31][ks 0..3][lane 0..63][8 bf16]; frag value j =
// W1[e][d = ks*32 + (lane>>4)*8 + j][h = ht*16 + (lane&15)]
//
// W2 path: reads already contiguous.
// W2F layout: [e][ht 0..31][ot 0..7][lane 0..63][4 bf16]; frag value j =
// W2[e][h = ht*16 + (lane>>4)*4 + j][o = ot*16 + (lane&15)]
#define W1_BLOCKS (NE * 4)
__global__ __launch_bounds__(256) void pack_weights(
    const float* __restrict__ W1, const float* __restrict__ W2,
    ushort* __restrict__ W1F, ushort* __restrict__ W2F) {
  __shared__ __align__(16) float T[32 * 132];   // 16.9 KB, shared by both paths
  const int tid = threadIdx.x;

  if ((int)blockIdx.x < W1_BLOCKS) {
    const int e = blockIdx.x >> 2, ks = blockIdx.x & 3;
    const float* We = W1 + (size_t)e * (DIN * DH) + (size_t)(ks * 32) * DH;
    const int r = tid >> 3, c0 = (tid & 7) * 16;   // load map: contiguous 64B/thread
    const int lane = tid & 63, wid = tid >> 6;
    const int q = lane >> 4, l16 = lane & 15;
    for (int hc = 0; hc < 4; ++hc) {
      if (hc) __syncthreads();                    // T reuse: reads done before rewrite
      const float* src = We + (size_t)r * DH + hc * 128 + c0;
      float4 v0 = *(const float4*)(src + 0);
      float4 v1 = *(const float4*)(src + 4);
      float4 v2 = *(const float4*)(src + 8);
      float4 v3 = *(const float4*)(src + 12);
      float* t = &T[r * 132 + c0];
      *(float4*)(t + 0) = v0; *(float4*)(t + 4)  = v1;
      *(float4*)(t + 8) = v2; *(float4*)(t + 12) = v3;
      __syncthreads();
#pragma unroll
      for (int i = 0; i < 2; ++i) {
        const int htl = wid + 4 * i;              // 0..7
        const int ht  = hc * 8 + htl;
        float g[8];
#pragma unroll
        for (int j = 0; j < 8; ++j) g[j] = T[(8 * q + j) * 132 + 16 * htl + l16];
        float4 a; a.x = g[0]; a.y = g[1]; a.z = g[2]; a.w = g[3];
        float4 b; b.x = g[4]; b.y = g[5]; b.z = g[6]; b.w = g[7];
        *(s8v*)(W1F + ((((size_t)e * 32 + ht) * 4) + ks) * 512 + lane * 8) = pack8(a, b);
      }
    }
  } else {
    const int bb = (int)blockIdx.x - W1_BLOCKS;
    const int e = bb >> 5, ht = bb & 31;
    float (*T2)[132] = (float (*)[132])T;
    const int h = tid >> 4, c16 = tid & 15;
    const float* src = W2 + (size_t)e * (DH * DOUT) + (size_t)(ht * 16 + h) * DOUT + c16 * 8;
    float4 v0 = *(const float4*)src;
    float4 v1 = *(const float4*)(src + 4);
    float* trow = &T2[h][c16 * 8];
    *(float4*)(trow + 0) = v0; *(float4*)(trow + 4) = v1;
    __syncthreads();
    const int lane = tid & 63;
    const int q = lane >> 4, l16 = lane & 15;
#pragma unroll
    for (int i = 0; i < 2; ++i) {
      int ot = (tid >> 6) + i * 4;
      float g0 = T2[4 * q + 0][ot * 16 + l16];
      float g1 = T2[4 * q + 1][ot * 16 + l16];
      float g2 = T2[4 * q + 2][ot * 16 + l16];
      float g3 = T2[4 * q + 3][ot * 16 + l16];
      union { s4v v; __hip_bfloat162 h2[2]; } u;
      u.h2[0] = pk2(g0, g1); u.h2[1] = pk2(g2, g3);
      *(s4v*)(W2F + (((size_t)e * 32 + ht) * 8 + ot) * 256 + lane * 4) = u.v;
    }
  }
}

// ---------------- fused main kernel ----------------
// Block = 128 tokens of one expert, 4 waves; wave w owns m-range [32w, 32w+32).
// X frags live in VGPRs for the whole block. Stage1 (K=32): Ht = W1 . X^T ->
// D regs ARE the K16 A-frag after gelu+pack. Stage2 (K=16): out += gelu(H).W2.
//
// OCCUPANCY is the round-7 lever. History: r3/r6 measured Occ 28%, MfmaUtil
// ~29%, VALUBusy ~40% (superset incl MFMA) -> ~60% of time neither pipe
// issues = latency-bound, too few resident waves. Barrier-halving (r6) was
// NEUTRAL -> sync count not the stall. r4 proved a forced 30-reg deficit
// ((256,5)=102 cap vs ~132 need) spills oacc: 4.2GB scratch, 6x slower.
// This version pays the occupancy price properly:
//   - LDS 32KB (2 buffers, depth-1)   -> 4 blocks x 32KB = 128KB <= 160KB
//   - regs <= 128 ((256,4) cap): af held as 2-reg batches, bfr as 4-wide
//     rounds; static peak ~118-126. Tripwire: if WRITE_SIZE >> 131MB it
//     spilled -> revert to (256,3).
// Loop (single barrier, wait BEFORE barrier for cross-wave LDS visibility):
//   WAIT_VM(0)  -- retire my chunk-c loads (issued last iter; ~1 chunk slack,
//                  weights are L2-resident via XCD swizzle so this is ~free)
//   BAR         -- all waves retired c => chunk-c LDS visible to all;
//                  all waves finished compute c-1 => buf^1 free (WAR)
//   stage(c+1)  -- depth-1 prefetch into buf^1
//   compute c from buf
__global__ __launch_bounds__(256, 4) void moe_fused(
    const float* __restrict__ X, const ushort* __restrict__ W1F,
    const ushort* __restrict__ W2F, float* __restrict__ Out) {
  __shared__ __align__(16) ushort W1s[2][4096];  // chunk: 2 htiles x 4 ks x 512
  __shared__ __align__(16) ushort W2s[2][4096];  // chunk: 2 htiles x 8 ot x 256

  const int tid  = threadIdx.x;
  const int lane = tid & 63;
  const int wid  = tid >> 6;
  const int q    = lane >> 4;
  const int l16  = lane & 15;

  // XCD swizzle: grid 2048 = 8 XCDs x 256 blocks (round-robin assumption).
  // XCD x gets work ids [x*256, x*256+256) = experts [x*16, x*16+16), all tiles.
  const int bid  = blockIdx.x;
  const int wk   = ((bid & 7) << 8) | (bid >> 3);
  const int e    = wk >> 4;
  const int tile = wk & 15;

  const float* Xe  = X + ((size_t)e * NT + (size_t)tile * 128) * DIN;
  const ushort* W1e = W1F + (size_t)e * 65536;
  const ushort* W2e = W2F + (size_t)e * 65536;
  float* Oe = Out + ((size_t)e * NT + (size_t)tile * 128) * DOUT;

  // ---- load this wave's X fragments into registers (once) ----
  s8v xf[2][4];
#pragma unroll
  for (int mt = 0; mt < 2; ++mt) {
#pragma unroll
    for (int ks = 0; ks < 4; ++ks) {
      const float* p = Xe + (size_t)(wid * 32 + mt * 16 + l16) * DIN + ks * 32 + q * 8;
      float4 v0 = *(const float4*)p;
      float4 v1 = *(const float4*)(p + 4);
      xf[mt][ks] = pack8(v0, v1);
    }
  }

  const f4v zero4 = {0.0f, 0.0f, 0.0f, 0.0f};
  f4v oacc[2][8];
#pragma unroll
  for (int mt = 0; mt < 2; ++mt)
#pragma unroll
    for (int ot = 0; ot < 8; ++ot) oacc[mt][ot] = zero4;

  // issue 4 global_load_lds per thread for one chunk (2x W1 + 2x W2)
  auto stage = [&](int chunk, int b) {
    const ushort* g1 = W1e + chunk * 4096;
    const ushort* g2 = W2e + chunk * 4096;
#pragma unroll
    for (int i = 0; i < 2; ++i) {
      int u = i * 256 + tid;
      GLOAD16(g1 + u * 8, &W1s[b][u * 8]);
      GLOAD16(g2 + u * 8, &W2s[b][u * 8]);
    }
  };

  // keep the xf float4 loads ordered before the staged GLOADs so the vmcnt
  // bookkeeping in the loop counts only weight loads
  asm volatile("" ::: "memory");

  // ---- prologue: chunk 0 into buf 0 ----
  stage(0, 0);

  for (int c = 0; c < 16; ++c) {
    const int buf = c & 1;
    WAIT_VM(0);   // retire MY chunk-c loads (only VMEM outstanding; ~free,
                  // they were issued a full chunk-period ago)
    BAR();        // all waves retired c -> LDS chunk c visible everywhere;
                  // compute c-1 done by all -> buf^1 safe to restage
    if (c < 15) stage(c + 1, buf ^ 1);

#pragma unroll
    for (int hl = 0; hl < 2; ++hl) {
      // stage 1: K=32 over d, one 16-h tile; af in 2-reg batches (reg slim)
      f4v hacc[2]; hacc[0] = zero4; hacc[1] = zero4;
#pragma unroll
      for (int kp = 0; kp < 2; ++kp) {
        s8v af0 = *(const s8v*)&W1s[buf][(hl * 4 + kp * 2 + 0) * 512 + lane * 8];
        s8v af1 = *(const s8v*)&W1s[buf][(hl * 4 + kp * 2 + 1) * 512 + lane * 8];
        __builtin_amdgcn_s_setprio(1);
        hacc[0] = MFMA32(af0, xf[0][kp * 2 + 0], hacc[0]);
        hacc[1] = MFMA32(af0, xf[1][kp * 2 + 0], hacc[1]);
        hacc[0] = MFMA32(af1, xf[0][kp * 2 + 1], hacc[0]);
        hacc[1] = MFMA32(af1, xf[1][kp * 2 + 1], hacc[1]);
        __builtin_amdgcn_s_setprio(0);
      }
      // gelu + pack: D regs (m=l16, h=4q+r) == K16 A-frag (row=l16, k=4q+j)
      s4v a2[2];
#pragma unroll
      for (int mt = 0; mt < 2; ++mt) {
        union { s4v v; __hip_bfloat162 h2[2]; } u;
        u.h2[0] = pk2(gelu_f(hacc[mt][0]), gelu_f(hacc[mt][1]));
        u.h2[1] = pk2(gelu_f(hacc[mt][2]), gelu_f(hacc[mt][3]));
        a2[mt] = u.v;
      }
      // stage 2: K=16, 8 o-tiles in 2 rounds of 4 (bfr reg slim)
#pragma unroll
      for (int op = 0; op < 2; ++op) {
        s4v b0 = *(const s4v*)&W2s[buf][(hl * 8 + op * 4 + 0) * 256 + lane * 4];
        s4v b1 = *(const s4v*)&W2s[buf][(hl * 8 + op * 4 + 1) * 256 + lane * 4];
        s4v b2 = *(const s4v*)&W2s[buf][(hl * 8 + op * 4 + 2) * 256 + lane * 4];
        s4v b3 = *(const s4v*)&W2s[buf][(hl * 8 + op * 4 + 3) * 256 + lane * 4];
        __builtin_amdgcn_s_setprio(1);
        oacc[0][op * 4 + 0] = MFMA16(a2[0], b0, oacc[0][op * 4 + 0]);
        oacc[1][op * 4 + 0] = MFMA16(a2[1], b0, oacc[1][op * 4 + 0]);
        oacc[0][op * 4 + 1] = MFMA16(a2[0], b1, oacc[0][op * 4 + 1]);
        oacc[1][op * 4 + 1] = MFMA16(a2[1], b1, oacc[1][op * 4 + 1]);
        oacc[0][op * 4 + 2] = MFMA16(a2[0], b2, oacc[0][op * 4 + 2]);
        oacc[1][op * 4 + 2] = MFMA16(a2[1], b2, oacc[1][op * 4 + 2]);
        oacc[0][op * 4 + 3] = MFMA16(a2[0], b3, oacc[0][op * 4 + 3]);
        oacc[1][op * 4 + 3] = MFMA16(a2[1], b3, oacc[1][op * 4 + 3]);
        __builtin_amdgcn_s_setprio(0);
      }
    }
  }

  // ---- epilogue: D layout col=o=l16, row m = 4q + r ----
#pragma unroll
  for (int mt = 0; mt < 2; ++mt) {
    const int mb = wid * 32 + mt * 16 + 4 * q;
#pragma unroll
    for (int ot = 0; ot < 8; ++ot) {
      float* p = Oe + (size_t)mb * DOUT + ot * 16 + l16;
      p[0 * DOUT] = oacc[mt][ot][0];
      p[1 * DOUT] = oacc[mt][ot][1];
      p[2 * DOUT] = oacc[mt][ot][2];
      p[3 * DOUT] = oacc[mt][ot][3];
    }
  }
}

extern "C" void kernel_launch(void* const* d_in, const int* in_sizes, int n_in,
                              void* d_out, int out_size, void* d_ws, size_t ws_size,
                              hipStream_t stream) {
  const float* X  = (const float*)d_in[0];
  const float* W1 = (const float*)d_in[1];
  const float* W2 = (const float*)d_in[2];
  float* Out = (float*)d_out;

  ushort* W1F = (ushort*)d_ws;                             // 128 KB/expert = 16.8 MB
  ushort* W2F = (ushort*)d_ws + (size_t)NE * 65536;        // 128 KB/expert = 16.8 MB

  pack_weights<<<NE * 4 + NE * 32, 256, 0, stream>>>(W1, W2, W1F, W2F);
  moe_fused<<<NE * (NT / 128), 256, 0, stream>>>(X, W1F, W2F, Out);
}